// Round 1
// baseline (474.284 us; speedup 1.0000x reference)
//
#include <hip/hip_runtime.h>
#include <hip/hip_bf16.h>

// Head-axis-softmax SDPA, B=2 S=2048 N=16 D=64, fp32 in/out.
// softmax is over HEADS (n), so it is local per (b,q,k): no online-softmax,
// and k-partials are additive -> k-split across blocks + atomicAdd epilogue.
//
// Block = 1024 threads = 16 waves; wave n == head n (all heads must be
// co-resident for the cross-head softmax). TQ=32 q-rows per block, TK=32
// keys per iteration, KSPLIT=2 so grid = 64*2*2 = 256 blocks (1 per CU).

#define B_ 2
#define S_ 2048
#define N_ 16
#define D_ 64
#define TQ 32
#define TK 32
#define KSPLIT 2
#define ITERS (S_ / TK / KSPLIT)  // 32 k-tiles per block

typedef __bf16 bf16x8 __attribute__((ext_vector_type(8)));
typedef float  f32x16 __attribute__((ext_vector_type(16)));

#define PK 40  // padded key-stride of pbuf rows: 80B = 16B-aligned, bank-spread

__global__ __launch_bounds__(1024) void sdpa_headsm_kernel(
    const float* __restrict__ Q, const float* __restrict__ K,
    const float* __restrict__ V, const int* __restrict__ M,
    float* __restrict__ O)
{
    // p/w buffer: [head][q][key+pad] bf16. Written by wave n (C-layout scatter),
    // reduced across n by (q,k)-threads, re-read as MFMA A-fragments (b128).
    __shared__ __align__(16) __bf16 pbuf[N_][TQ][PK];

    const int tid  = threadIdx.x;
    const int n    = tid >> 6;    // head == wave
    const int lane = tid & 63;
    const int lo   = lane & 31;
    const int hi   = lane >> 5;

    const int qt = blockIdx.x;
    const int b  = blockIdx.y;
    const int kz = blockIdx.z;
    const int q0 = qt * TQ;

    // ---- Q A-fragments, loaded once (A: m = lane&31, k = hi*8 + j, per 16-chunk)
    bf16x8 qf[4];
    {
        const float* qrow = Q + (((size_t)b * S_ + (size_t)(q0 + lo)) * N_ + n) * D_;
        #pragma unroll
        for (int ks = 0; ks < 4; ++ks) {
            const float* p = qrow + ks * 16 + hi * 8;
            float4 a0 = *(const float4*)(p);
            float4 a1 = *(const float4*)(p + 4);
            bf16x8 f;
            f[0] = (__bf16)a0.x; f[1] = (__bf16)a0.y;
            f[2] = (__bf16)a0.z; f[3] = (__bf16)a0.w;
            f[4] = (__bf16)a1.x; f[5] = (__bf16)a1.y;
            f[6] = (__bf16)a1.z; f[7] = (__bf16)a1.w;
            qf[ks] = f;
        }
    }

    f32x16 o0 = {};  // out cols d =  0..31  (C layout)
    f32x16 o1 = {};  // out cols d = 32..63

    for (int it = 0; it < ITERS; ++it) {
        const int k0 = (kz * ITERS + it) * TK;

        // ---- QK^T: K B-frags straight from global (fp32 -> bf16).
        // B: n-col = key = lane&31, k = d = ks*16 + hi*8 + j  (8 contiguous d)
        f32x16 s = {};
        #pragma unroll
        for (int ks = 0; ks < 4; ++ks) {
            const float* krow = K + (((size_t)b * S_ + (size_t)(k0 + lo)) * N_ + n) * D_
                                  + ks * 16 + hi * 8;
            float4 a0 = *(const float4*)(krow);
            float4 a1 = *(const float4*)(krow + 4);
            bf16x8 f;
            f[0] = (__bf16)a0.x; f[1] = (__bf16)a0.y;
            f[2] = (__bf16)a0.z; f[3] = (__bf16)a0.w;
            f[4] = (__bf16)a1.x; f[5] = (__bf16)a1.y;
            f[6] = (__bf16)a1.z; f[7] = (__bf16)a1.w;
            s = __builtin_amdgcn_mfma_f32_32x32x16_bf16(qf[ks], f, s, 0, 0, 0);
        }

        // ---- mask + exp -> p (bf16) into pbuf[n][row][col]
        // C/D: col = lane&31, row = (r&3) + 8*(r>>2) + 4*hi
        #pragma unroll
        for (int r = 0; r < 16; ++r) {
            const int row = (r & 3) + 8 * (r >> 2) + 4 * hi;
            const int m = M[(size_t)b * S_ * S_ + (size_t)(q0 + row) * S_ + (k0 + lo)];
            const float e = m ? __expf(s[r] * 0.125f) : 0.0f;  // mask==0 -> exp(-inf)=0
            pbuf[n][row][lo] = (__bf16)e;
        }

        // ---- V B-frags (issue early to overlap barriers).
        // B: n-col = d = dt*32 + lane&31, k = key = kstep*16 + hi*8 + j
        bf16x8 vf[2][2];
        #pragma unroll
        for (int kstep = 0; kstep < 2; ++kstep) {
            #pragma unroll
            for (int dt = 0; dt < 2; ++dt) {
                bf16x8 f;
                #pragma unroll
                for (int j = 0; j < 8; ++j) {
                    const int key = k0 + kstep * 16 + hi * 8 + j;
                    f[j] = (__bf16)V[(((size_t)b * S_ + key) * N_ + n) * D_ + dt * 32 + lo];
                }
                vf[kstep][dt] = f;
            }
        }

        __syncthreads();  // p complete for all heads

        // ---- cross-head softmax denom + in-place normalize.
        // thread t owns (q = t>>5, k = t&31); reads/writes only its 16 n-slots.
        {
            const int tq = tid >> 5;
            const int tk = tid & 31;
            float pv[16];
            float sum = 0.f;
            #pragma unroll
            for (int j = 0; j < 16; ++j) { pv[j] = (float)pbuf[j][tq][tk]; sum += pv[j]; }
            const float rd = 1.0f / sum;  // sum==0 (all masked) -> inf -> 0*inf=NaN, matches ref
            #pragma unroll
            for (int j = 0; j < 16; ++j) pbuf[j][tq][tk] = (__bf16)(pv[j] * rd);
        }

        __syncthreads();  // w ready

        // ---- PV: A = W[q][key] from pbuf (b128, conflict-free via PK=40 pad)
        #pragma unroll
        for (int kstep = 0; kstep < 2; ++kstep) {
            const __bf16* wp = &pbuf[n][lo][kstep * 16 + hi * 8];
            bf16x8 wf = *(const bf16x8*)wp;
            o0 = __builtin_amdgcn_mfma_f32_32x32x16_bf16(wf, vf[kstep][0], o0, 0, 0, 0);
            o1 = __builtin_amdgcn_mfma_f32_32x32x16_bf16(wf, vf[kstep][1], o1, 0, 0, 0);
        }

        __syncthreads();  // protect pbuf before next iteration's p-writes
    }

    // ---- epilogue: k-split partials combine via device-scope atomics
    #pragma unroll
    for (int r = 0; r < 16; ++r) {
        const int row = (r & 3) + 8 * (r >> 2) + 4 * hi;
        const size_t base = (((size_t)b * N_ + n) * S_ + (q0 + row)) * (size_t)D_;
        atomicAdd(&O[base + lo],        o0[r]);
        atomicAdd(&O[base + 32 + lo],   o1[r]);
    }
}

extern "C" void kernel_launch(void* const* d_in, const int* in_sizes, int n_in,
                              void* d_out, int out_size, void* d_ws, size_t ws_size,
                              hipStream_t stream) {
    const float* Q = (const float*)d_in[0];
    const float* K = (const float*)d_in[1];
    const float* V = (const float*)d_in[2];
    const int*   M = (const int*)d_in[3];
    float* O = (float*)d_out;

    // d_out is poisoned before every timed launch; zero it for the atomic epilogue.
    hipMemsetAsync(d_out, 0, (size_t)out_size * sizeof(float), stream);

    dim3 grid(S_ / TQ, B_, KSPLIT);
    sdpa_headsm_kernel<<<grid, dim3(1024), 0, stream>>>(Q, K, V, M, O);
}

// Round 2
// 381.525 us; speedup vs baseline: 1.2431x; 1.2431x over previous
//
#include <hip/hip_runtime.h>
#include <hip/hip_bf16.h>

// Head-axis-softmax SDPA, B=2 S=2048 N=16 D=64, fp32 in/out.
// softmax is over HEADS (n), so it is local per (b,q,k): no online-softmax,
// and k-partials are additive -> k-split across blocks + atomicAdd epilogue.
//
// Block = 1024 threads = 16 waves; wave n == head n (all heads must be
// co-resident for the cross-head softmax). TQ=32 q-rows per block, TK=32
// keys per iteration.
//
// R2: KSPLIT=4 -> grid 512 -> 2 blocks/CU co-resident (VGPR=64 is exactly the
// 8-waves/SIMD boundary; adding ANY registers halves occupancy — keep <=64).
// Mask moved from exp phase (16 loads/thread/iter) to reduce phase (1 load).

#define B_ 2
#define S_ 2048
#define N_ 16
#define D_ 64
#define TQ 32
#define TK 32
#define KSPLIT 4
#define ITERS (S_ / TK / KSPLIT)  // 16 k-tiles per block

typedef __bf16 bf16x8 __attribute__((ext_vector_type(8)));
typedef float  f32x16 __attribute__((ext_vector_type(16)));

#define PK 40  // padded key-stride of pbuf rows: 80B = 16B-aligned, bank-spread

__global__ __launch_bounds__(1024) void sdpa_headsm_kernel(
    const float* __restrict__ Q, const float* __restrict__ K,
    const float* __restrict__ V, const int* __restrict__ M,
    float* __restrict__ O)
{
    // p/w buffer: [head][q][key+pad] bf16. Written by wave n (C-layout scatter),
    // reduced across n by (q,k)-threads, re-read as MFMA A-fragments (b128).
    __shared__ __align__(16) __bf16 pbuf[N_][TQ][PK];

    const int tid  = threadIdx.x;
    const int n    = tid >> 6;    // head == wave
    const int lane = tid & 63;
    const int lo   = lane & 31;
    const int hi   = lane >> 5;

    const int qt = blockIdx.x;
    const int b  = blockIdx.y;
    const int kz = blockIdx.z;
    const int q0 = qt * TQ;

    // ---- Q A-fragments, loaded once (A: m = lane&31, k = hi*8 + j, per 16-chunk)
    bf16x8 qf[4];
    {
        const float* qrow = Q + (((size_t)b * S_ + (size_t)(q0 + lo)) * N_ + n) * D_;
        #pragma unroll
        for (int ks = 0; ks < 4; ++ks) {
            const float* p = qrow + ks * 16 + hi * 8;
            float4 a0 = *(const float4*)(p);
            float4 a1 = *(const float4*)(p + 4);
            bf16x8 f;
            f[0] = (__bf16)a0.x; f[1] = (__bf16)a0.y;
            f[2] = (__bf16)a0.z; f[3] = (__bf16)a0.w;
            f[4] = (__bf16)a1.x; f[5] = (__bf16)a1.y;
            f[6] = (__bf16)a1.z; f[7] = (__bf16)a1.w;
            qf[ks] = f;
        }
    }

    f32x16 o0 = {};  // out cols d =  0..31  (C layout)
    f32x16 o1 = {};  // out cols d = 32..63

    for (int it = 0; it < ITERS; ++it) {
        const int k0 = (kz * ITERS + it) * TK;

        // ---- QK^T: K B-frags straight from global (fp32 -> bf16).
        // B: n-col = key = lane&31, k = d = ks*16 + hi*8 + j  (8 contiguous d)
        f32x16 s = {};
        #pragma unroll
        for (int ks = 0; ks < 4; ++ks) {
            const float* krow = K + (((size_t)b * S_ + (size_t)(k0 + lo)) * N_ + n) * D_
                                  + ks * 16 + hi * 8;
            float4 a0 = *(const float4*)(krow);
            float4 a1 = *(const float4*)(krow + 4);
            bf16x8 f;
            f[0] = (__bf16)a0.x; f[1] = (__bf16)a0.y;
            f[2] = (__bf16)a0.z; f[3] = (__bf16)a0.w;
            f[4] = (__bf16)a1.x; f[5] = (__bf16)a1.y;
            f[6] = (__bf16)a1.z; f[7] = (__bf16)a1.w;
            s = __builtin_amdgcn_mfma_f32_32x32x16_bf16(qf[ks], f, s, 0, 0, 0);
        }

        // ---- V B-frags, issued BEFORE the exp loop so the 32 scalar-load
        // latencies overlap exp VALU work + barrier wait.
        // B: n-col = d = dt*32 + lane&31, k = key = kstep*16 + hi*8 + j
        bf16x8 vf[2][2];
        #pragma unroll
        for (int kstep = 0; kstep < 2; ++kstep) {
            #pragma unroll
            for (int dt = 0; dt < 2; ++dt) {
                bf16x8 f;
                #pragma unroll
                for (int j = 0; j < 8; ++j) {
                    const int key = k0 + kstep * 16 + hi * 8 + j;
                    f[j] = (__bf16)V[(((size_t)b * S_ + key) * N_ + n) * D_ + dt * 32 + lo];
                }
                vf[kstep][dt] = f;
            }
        }

        // ---- exp -> p (bf16) into pbuf[n][row][col]  (mask applied in reduce)
        // C/D: col = lane&31, row = (r&3) + 8*(r>>2) + 4*hi
        #pragma unroll
        for (int r = 0; r < 16; ++r) {
            const int row = (r & 3) + 8 * (r >> 2) + 4 * hi;
            pbuf[n][row][lo] = (__bf16)__expf(s[r] * 0.125f);
        }

        __syncthreads();  // p complete for all heads

        // ---- cross-head softmax denom + in-place normalize + mask.
        // thread t owns (q = t>>5, k = t&31); reads/writes only its 16 n-slots.
        // mask is uniform across heads: ONE coalesced load per thread.
        {
            const int tq = tid >> 5;
            const int tk = tid & 31;
            const int m = M[(size_t)b * S_ * S_ + (size_t)(q0 + tq) * S_ + (k0 + tk)];
            float pv[16];
            float sum = 0.f;
            #pragma unroll
            for (int j = 0; j < 16; ++j) { pv[j] = (float)pbuf[j][tq][tk]; sum += pv[j]; }
            // mask==0: ref's softmax over all-(-inf) heads -> NaN weights
            const float rd = m ? (1.0f / sum) : __builtin_nanf("");
            #pragma unroll
            for (int j = 0; j < 16; ++j) pbuf[j][tq][tk] = (__bf16)(pv[j] * rd);
        }

        __syncthreads();  // w ready

        // ---- PV: A = W[q][key] from pbuf (b128, conflict-free via PK=40 pad)
        #pragma unroll
        for (int kstep = 0; kstep < 2; ++kstep) {
            const __bf16* wp = &pbuf[n][lo][kstep * 16 + hi * 8];
            bf16x8 wf = *(const bf16x8*)wp;
            o0 = __builtin_amdgcn_mfma_f32_32x32x16_bf16(wf, vf[kstep][0], o0, 0, 0, 0);
            o1 = __builtin_amdgcn_mfma_f32_32x32x16_bf16(wf, vf[kstep][1], o1, 0, 0, 0);
        }

        __syncthreads();  // protect pbuf before next iteration's p-writes
    }

    // ---- epilogue: k-split partials combine via device-scope atomics
    #pragma unroll
    for (int r = 0; r < 16; ++r) {
        const int row = (r & 3) + 8 * (r >> 2) + 4 * hi;
        const size_t base = (((size_t)b * N_ + n) * S_ + (q0 + row)) * (size_t)D_;
        atomicAdd(&O[base + lo],        o0[r]);
        atomicAdd(&O[base + 32 + lo],   o1[r]);
    }
}

extern "C" void kernel_launch(void* const* d_in, const int* in_sizes, int n_in,
                              void* d_out, int out_size, void* d_ws, size_t ws_size,
                              hipStream_t stream) {
    const float* Q = (const float*)d_in[0];
    const float* K = (const float*)d_in[1];
    const float* V = (const float*)d_in[2];
    const int*   M = (const int*)d_in[3];
    float* O = (float*)d_out;

    // d_out is poisoned before every timed launch; zero it for the atomic epilogue.
    hipMemsetAsync(d_out, 0, (size_t)out_size * sizeof(float), stream);

    dim3 grid(S_ / TQ, B_, KSPLIT);
    sdpa_headsm_kernel<<<grid, dim3(1024), 0, stream>>>(Q, K, V, M, O);
}